// Round 9
// baseline (207.702 us; speedup 1.0000x reference)
//
#include <hip/hip_runtime.h>
#include <hip/hip_bf16.h>
#include <stdint.h>

// Problem constants
#define TOKS   262144      // B*S = 32*8192
#define NGRP   16384       // B*G = 32*512
#define EMB    1024
#define HD     64

using bf16x8 = __attribute__((ext_vector_type(8))) short;   // 8 bf16 (4 VGPRs) MFMA operand
using f32x4  = __attribute__((ext_vector_type(4))) float;   // MFMA accumulator

__device__ __forceinline__ unsigned pack2(float a, float b) {
    union { __hip_bfloat162 h; unsigned u; } cvt;
    cvt.h = __float22bfloat162_rn(make_float2(a, b));   // RNE pk-convert
    return cvt.u;
}
__device__ __forceinline__ bf16x8 cvt8(float4 v0, float4 v1) {
    uint4 u;
    u.x = pack2(v0.x, v0.y);
    u.y = pack2(v0.z, v0.w);
    u.z = pack2(v1.x, v1.y);
    u.w = pack2(v1.z, v1.w);
    return __builtin_bit_cast(bf16x8, u);
}
// 3-term row swizzle: 16B-chunk XOR mask within each 128B (64-el) stripe.
__device__ __forceinline__ int swz(int r) {
    return ((r ^ (r >> 2) ^ (r >> 4)) & 7) << 3;
}

// ---------------------------------------------------------------------------
// K0: pack Wo (fp32 [1024][1024]) into MFMA-fragment-linear bf16 (blocks 0..511):
//       packed[((kc*64 + nb)*64 + l)*8 + e] = bf16(Wo[nb*16 + (l&15)][kc*32 + (l>>4)*8 + e])
//     Wq|Wk|Wv (fp32 [64][64]) -> bf16 packed [3][4096] (blocks 512..523).
// ---------------------------------------------------------------------------
__global__ __launch_bounds__(256) void k_cvt(const float* __restrict__ wo,
                                             const float* __restrict__ wq,
                                             const float* __restrict__ wk,
                                             const float* __restrict__ wv,
                                             unsigned short* __restrict__ wob,
                                             unsigned short* __restrict__ wqkvb) {
    int bid = blockIdx.x;
    if (bid < 512) {
        int tid = bid * 256 + threadIdx.x;   // 0..131071, 8 elems each
        int kc  = tid >> 12;                 // k-chunk of 32, 0..31
        int nb  = (tid >> 6) & 63;           // n-block of 16
        int l   = tid & 63;                  // lane within fragment
        int n   = nb * 16 + (l & 15);
        int k   = kc * 32 + (l >> 4) * 8;
        const float* src = wo + (size_t)n * 1024 + k;
        float4 v0 = *(const float4*)(src);
        float4 v1 = *(const float4*)(src + 4);
        *(bf16x8*)(wob + (size_t)tid * 8) = cvt8(v0, v1);
    } else {
        int b = bid - 512;                  // 0..11
        int m = b >> 2;
        const float* src = (m == 0) ? wq : ((m == 1) ? wk : wv);
        int idx = ((b & 3) * 256 + threadIdx.x) * 4;
        float4 v = *(const float4*)(src + idx);
        uint2 p;
        p.x = pack2(v.x, v.y);
        p.y = pack2(v.z, v.w);
        *(uint2*)(wqkvb + m * 4096 + idx) = p;
    }
}

// ---------------------------------------------------------------------------
// K1 (MEGA): fused attention + output GEMM, SOFTWARE-PIPELINED PHASES.
// Structure identical to round 8; ROUND-9 FIX: B-fragment kc-stride is
// 32768 shorts (64 frags x 512), round 8 erroneously used kc*65536 (read
// past wob for kc>=16 -> absmax 0.57). One-constant fix, clean A/B vs r7.
//
// Pipeline: step p = { attention pair p || GEMM chunk p-1 }, opposite order
// for waves 0-3 vs 4-7 (w and w+4 share a SIMD -> each SIMD always hosts
// one MFMA-firing wave and one attention wave). Barrier per step orders
// pair-(p-1) writes before chunk-(p-1) reads; pair-p write stripes
// {2p,2p+1,8+2p,8+2p+1} disjoint from chunk-(p-1) read stripes. Final
// chunk(3) + epilogue after the loop. Chunk kc-order permutes fp32
// accumulation order (ulp-class absmax shift vs r7 allowed).
// ---------------------------------------------------------------------------
#define SCL 0.0450842200278f   /* log2(e)/32 */

#define MFMA_B16(A, B, Cc) __builtin_amdgcn_mfma_f32_16x16x32_bf16(A, B, Cc, 0, 0, 0)

__global__ __launch_bounds__(512, 2) void k_mega(const float* __restrict__ x,
                                                 const unsigned short* __restrict__ wqkv,
                                                 const unsigned short* __restrict__ wob,
                                                 const float* __restrict__ bias,
                                                 float* __restrict__ C) {
    extern __shared__ __align__(16) unsigned short lds[];
    unsigned short* out2s = lds;               // [64][1024] bf16 A-tile (128 KB)
    unsigned short* kscr  = lds + 65536;       // [8 waves][16][64] K-scratch (16 KB)

    const int t = threadIdx.x;
    const int w = t >> 6, l = t & 63;
    const int c = l & 15, q = l >> 4;
    const int bid   = blockIdx.x;
    const int batch = bid >> 3, q8r = bid & 7;
    unsigned short* kw = kscr + w * 1024;

    const int gbq = w >> 1;                    // wave-constant local group-block
    const int gc0 = (w & 1) * 8;               // wave's first column stripe

    // store masks for the 4 token-rows of a q-quadrant: rows 16q+gbq+4j
    const int mS0 = swz(16 * q + gbq);
    const int mS1 = swz(16 * q + gbq + 4);
    const int mS2 = swz(16 * q + gbq + 8);
    const int mS3 = swz(16 * q + gbq + 12);
    const int mkw = swz(c);                    // K-scratch read mask (row c)
    const int mqe = swz(c * 4 + gbq);          // energy Q-read mask (row 4c+gbq)
    const int mk0 = swz(4 * q);                // K-scratch write masks (rows 4q+j)
    const int mk1 = swz(4 * q + 1);
    const int mk2 = swz(4 * q + 2);
    const int mk3 = swz(4 * q + 3);

    const float* xb = x + ((size_t)bid * 1024 + c) * 64 + q * 8;
    const unsigned short* gBw = wob + (size_t)(w * 8) * 512 + (size_t)l * 8;

    f32x4 acc[4][8];
    #pragma unroll
    for (int m = 0; m < 4; ++m)
        #pragma unroll
        for (int nb = 0; nb < 8; ++nb)
            acc[m][nb] = (f32x4){0.f, 0.f, 0.f, 0.f};

    // ---- attention pair p: groups w*8 + 2p + {0,1} ----
    auto PAIR = [&](int p) {
        float4 xr[2][4];
        #pragma unroll
        for (int g = 0; g < 2; ++g) {
            const float* xp = xb + (size_t)(w * 8 + 2 * p + g) * 1024;
            xr[g][0] = *(const float4*)(xp);
            xr[g][1] = *(const float4*)(xp + 4);
            xr[g][2] = *(const float4*)(xp + 32);
            xr[g][3] = *(const float4*)(xp + 36);
        }
        bf16x8 xa[2][2];
        #pragma unroll
        for (int g = 0; g < 2; ++g) {
            xa[g][0] = cvt8(xr[g][0], xr[g][1]);
            xa[g][1] = cvt8(xr[g][2], xr[g][3]);
        }

        unsigned short* qs[2];
        qs[0] = out2s + (size_t)(16 * q + gbq) * 1024 + (gc0 + 2 * p) * 64;
        qs[1] = qs[0] + 64;

        // Q projection (both groups; W-frags shared)
        #pragma unroll
        for (int nb = 0; nb < 4; ++nb) {
            const unsigned short* wp = wqkv + (nb * 16 + c) * 64 + q * 8;
            bf16x8 w0 = *(const bf16x8*)(wp);
            bf16x8 w1 = *(const bf16x8*)(wp + 32);
            #pragma unroll
            for (int g = 0; g < 2; ++g) {
                f32x4 a2 = (f32x4){0.f, 0.f, 0.f, 0.f};
                a2 = MFMA_B16(xa[g][0], w0, a2);
                a2 = MFMA_B16(xa[g][1], w1, a2);
                unsigned u01 = pack2(a2[0], a2[1]);
                unsigned u23 = pack2(a2[2], a2[3]);
                const int d = nb * 16 + c;
                qs[g][(d ^ mS0)]             = (unsigned short)u01;
                qs[g][4 * 1024 + (d ^ mS1)]  = (unsigned short)(u01 >> 16);
                qs[g][8 * 1024 + (d ^ mS2)]  = (unsigned short)u23;
                qs[g][12 * 1024 + (d ^ mS3)] = (unsigned short)(u23 >> 16);
            }
        }

        // V projection (both groups) -> regs
        uint2 pkV[2][4];
        #pragma unroll
        for (int nb = 0; nb < 4; ++nb) {
            const unsigned short* wp = wqkv + 2 * 4096 + (nb * 16 + c) * 64 + q * 8;
            bf16x8 w0 = *(const bf16x8*)(wp);
            bf16x8 w1 = *(const bf16x8*)(wp + 32);
            #pragma unroll
            for (int g = 0; g < 2; ++g) {
                f32x4 a2 = (f32x4){0.f, 0.f, 0.f, 0.f};
                a2 = MFMA_B16(xa[g][0], w0, a2);
                a2 = MFMA_B16(xa[g][1], w1, a2);
                pkV[g][nb].x = pack2(a2[0], a2[1]);
                pkV[g][nb].y = pack2(a2[2], a2[3]);
            }
        }

        // K projection + energy, per group (shared kw scratch; same-wave DS order)
        f32x4 e[2];
        #pragma unroll
        for (int g = 0; g < 2; ++g) {
            #pragma unroll
            for (int nb = 0; nb < 4; ++nb) {
                const unsigned short* wp = wqkv + 4096 + (nb * 16 + c) * 64 + q * 8;
                bf16x8 w0 = *(const bf16x8*)(wp);
                bf16x8 w1 = *(const bf16x8*)(wp + 32);
                f32x4 a2 = (f32x4){0.f, 0.f, 0.f, 0.f};
                a2 = MFMA_B16(xa[g][0], w0, a2);
                a2 = MFMA_B16(xa[g][1], w1, a2);
                unsigned u01 = pack2(a2[0], a2[1]);
                unsigned u23 = pack2(a2[2], a2[3]);
                const int d = nb * 16 + c;
                const int kr = 4 * q;
                kw[(kr + 0) * 64 + (d ^ mk0)] = (unsigned short)u01;
                kw[(kr + 1) * 64 + (d ^ mk1)] = (unsigned short)(u01 >> 16);
                kw[(kr + 2) * 64 + (d ^ mk2)] = (unsigned short)u23;
                kw[(kr + 3) * 64 + (d ^ mk3)] = (unsigned short)(u23 >> 16);
            }
            e[g] = (f32x4){0.f, 0.f, 0.f, 0.f};
            const unsigned short* qrow = out2s + (size_t)(c * 4 + gbq) * 1024
                                               + (gc0 + 2 * p + g) * 64;
            #pragma unroll
            for (int kc2 = 0; kc2 < 2; ++kc2) {
                const int L = kc2 * 32 + q * 8;
                bf16x8 ka = *(const bf16x8*)(kw + c * 64 + (L ^ mkw));
                bf16x8 qb = *(const bf16x8*)(qrow + (L ^ mqe));
                e[g] = MFMA_B16(ka, qb, e[g]);
            }
        }

        // softmax (both groups)
        unsigned pa0[2], pa1[2];
        #pragma unroll
        for (int g = 0; g < 2; ++g) {
            float mx = fmaxf(fmaxf(e[g][0], e[g][1]), fmaxf(e[g][2], e[g][3]));
            mx = fmaxf(mx, __shfl_xor(mx, 16));
            mx = fmaxf(mx, __shfl_xor(mx, 32));
            float p0 = exp2f((e[g][0] - mx) * SCL);
            float p1 = exp2f((e[g][1] - mx) * SCL);
            float p2 = exp2f((e[g][2] - mx) * SCL);
            float p3 = exp2f((e[g][3] - mx) * SCL);
            float s = p0 + p1 + p2 + p3;
            s += __shfl_xor(s, 16);
            s += __shfl_xor(s, 32);
            float rinv = 1.0f / s;
            pa0[g] = pack2(p0 * rinv, p1 * rinv);   // j = 4q+0,1
            pa1[g] = pack2(p2 * rinv, p3 * rinv);   // j = 4q+2,3
        }

        // PV (both groups); output overwrites the Q stripe
        const int sh0 = (32 * q + c) & 63;
        const int sh1 = (32 * q + 16 + c) & 63;
        const int sv0 = 32 * (q & 1) + c;
        const int sv1 = sv0 + 16;
        const bool hi = (q >= 2);                   // k >= 16 -> zero pad
        #pragma unroll
        for (int g = 0; g < 2; ++g) {
            int a0 = __shfl((int)pa0[g], sh0);
            int a1 = __shfl((int)pa1[g], sh0);
            int a2 = __shfl((int)pa0[g], sh1);
            int a3 = __shfl((int)pa1[g], sh1);
            uint4 A2u;
            A2u.x = hi ? 0u : (unsigned)a0;
            A2u.y = hi ? 0u : (unsigned)a1;
            A2u.z = hi ? 0u : (unsigned)a2;
            A2u.w = hi ? 0u : (unsigned)a3;
            bf16x8 A2 = __builtin_bit_cast(bf16x8, A2u);

            #pragma unroll
            for (int nb = 0; nb < 4; ++nb) {
                uint4 B2u;
                B2u.x = (unsigned)__shfl((int)pkV[g][nb].x, sv0);
                B2u.y = (unsigned)__shfl((int)pkV[g][nb].y, sv0);
                B2u.z = (unsigned)__shfl((int)pkV[g][nb].x, sv1);
                B2u.w = (unsigned)__shfl((int)pkV[g][nb].y, sv1);
                bf16x8 B2 = __builtin_bit_cast(bf16x8, B2u);
                f32x4 o = (f32x4){0.f, 0.f, 0.f, 0.f};
                o = MFMA_B16(A2, B2, o);
                unsigned u01 = pack2(o[0], o[1]);
                unsigned u23 = pack2(o[2], o[3]);
                const int d = nb * 16 + c;
                qs[g][(d ^ mS0)]             = (unsigned short)u01;
                qs[g][4 * 1024 + (d ^ mS1)]  = (unsigned short)(u01 >> 16);
                qs[g][8 * 1024 + (d ^ mS2)]  = (unsigned short)u23;
                qs[g][12 * 1024 + (d ^ mS3)] = (unsigned short)(u23 >> 16);
            }
        }
    };

    // ---- GEMM chunk for pair cp: kc in {4cp..4cp+3} u {16+4cp..16+4cp+3} ----
    // B-frag address = gBw + kc*32768 + nb*512  (64 frags x 512 per kc slice).
    auto CHUNK = [&](int cp) {
        #pragma unroll
        for (int h = 0; h < 2; ++h) {
            #pragma unroll
            for (int kk = 0; kk < 4; ++kk) {
                const int kc = h * 16 + 4 * cp + kk;
                bf16x8 bb[8];
                #pragma unroll
                for (int nb = 0; nb < 8; ++nb)
                    bb[nb] = *(const bf16x8*)(gBw + (size_t)kc * 32768 + nb * 512);
                const int L = kc * 32 + q * 8;
                bf16x8 av[4];
                #pragma unroll
                for (int m = 0; m < 4; ++m)
                    av[m] = *(const bf16x8*)(out2s + (size_t)(m * 16 + c) * 1024
                                                   + (L ^ swz(m * 16 + c)));
                #pragma unroll
                for (int m = 0; m < 4; ++m)
                    #pragma unroll
                    for (int nb = 0; nb < 8; ++nb)
                        acc[m][nb] = MFMA_B16(av[m], bb[nb], acc[m][nb]);
            }
        }
    };

    // ---- pipelined steps: attention pair p || GEMM chunk p-1 ----
    // waves 0-3 and 4-7 run the two halves in opposite order; w and w+4
    // share a SIMD, so each SIMD always has one MFMA wave + one attn wave.
    #pragma unroll 1
    for (int p = 0; p < 4; ++p) {
        __syncthreads();   // pair p-1 writes complete before chunk p-1 reads
        if (w >= 4) {
            if (p > 0) CHUNK(p - 1);
            PAIR(p);
        } else {
            PAIR(p);
            if (p > 0) CHUNK(p - 1);
        }
    }
    __syncthreads();
    CHUNK(3);

    // ---- epilogue: bias + fp32 store. Local row lr = m*16 + q*4 + r:
    //      rg = batch*512 + (4m+q)*32 + (bid&7)*4 + r.
    float bc[8];
    #pragma unroll
    for (int nb = 0; nb < 8; ++nb) bc[nb] = bias[w * 128 + nb * 16 + c];
    #pragma unroll
    for (int m = 0; m < 4; ++m) {
        #pragma unroll
        for (int r = 0; r < 4; ++r) {
            const int rg = batch * 512 + (m * 4 + q) * 32 + q8r * 4 + r;
            float* cp2 = C + (size_t)rg * 1024 + w * 128 + c;
            #pragma unroll
            for (int nb = 0; nb < 8; ++nb)
                cp2[nb * 16] = acc[m][nb][r] + bc[nb];
        }
    }
}

// ---------------------------------------------------------------------------
extern "C" void kernel_launch(void* const* d_in, const int* in_sizes, int n_in,
                              void* d_out, int out_size, void* d_ws, size_t ws_size,
                              hipStream_t stream) {
    const float* x  = (const float*)d_in[0];
    const float* wq = (const float*)d_in[1];
    const float* wk = (const float*)d_in[2];
    const float* wv = (const float*)d_in[3];
    const float* wo = (const float*)d_in[4];
    const float* bo = (const float*)d_in[5];
    float* out = (float*)d_out;

    unsigned short* wob   = (unsigned short*)d_ws;           // 1024*1024 bf16 packed (2 MB)
    unsigned short* wqkvb = wob + (size_t)EMB * EMB;         // 3*4096 bf16 (24 KB)

    static int s_once = []() {
        hipFuncSetAttribute((const void*)k_mega,
                            hipFuncAttributeMaxDynamicSharedMemorySize, 147456);
        return 0;
    }();
    (void)s_once;

    k_cvt <<<524, 256, 0, stream>>>(wo, wq, wk, wv, wob, wqkvb);
    k_mega<<<256, 512, 147456, stream>>>(x, wqkvb, wob, bo, out);
}

// Round 10
// 207.617 us; speedup vs baseline: 1.0004x; 1.0004x over previous
//
#include <hip/hip_runtime.h>
#include <hip/hip_bf16.h>
#include <stdint.h>

// Problem constants
#define TOKS   262144      // B*S = 32*8192
#define NGRP   16384       // B*G = 32*512
#define EMB    1024
#define HD     64

using bf16x8 = __attribute__((ext_vector_type(8))) short;   // 8 bf16 (4 VGPRs) MFMA operand
using f32x4  = __attribute__((ext_vector_type(4))) float;   // MFMA accumulator

__device__ __forceinline__ unsigned pack2(float a, float b) {
    union { __hip_bfloat162 h; unsigned u; } cvt;
    cvt.h = __float22bfloat162_rn(make_float2(a, b));   // RNE pk-convert
    return cvt.u;
}
__device__ __forceinline__ bf16x8 cvt8(float4 v0, float4 v1) {
    uint4 u;
    u.x = pack2(v0.x, v0.y);
    u.y = pack2(v0.z, v0.w);
    u.z = pack2(v1.x, v1.y);
    u.w = pack2(v1.z, v1.w);
    return __builtin_bit_cast(bf16x8, u);
}
// 3-term row swizzle: 16B-chunk XOR mask within each 128B (64-el) stripe.
__device__ __forceinline__ int swz(int r) {
    return ((r ^ (r >> 2) ^ (r >> 4)) & 7) << 3;
}

// ---------------------------------------------------------------------------
// K0: pack Wo (fp32 [1024][1024]) into MFMA-fragment-linear bf16 (blocks 0..511):
//       packed[((kc*64 + nb)*64 + l)*8 + e] = bf16(Wo[nb*16 + (l&15)][kc*32 + (l>>4)*8 + e])
//     Wq|Wk|Wv (fp32 [64][64]) -> bf16 packed [3][4096] (blocks 512..523).
// ---------------------------------------------------------------------------
__global__ __launch_bounds__(256) void k_cvt(const float* __restrict__ wo,
                                             const float* __restrict__ wq,
                                             const float* __restrict__ wk,
                                             const float* __restrict__ wv,
                                             unsigned short* __restrict__ wob,
                                             unsigned short* __restrict__ wqkvb) {
    int bid = blockIdx.x;
    if (bid < 512) {
        int tid = bid * 256 + threadIdx.x;   // 0..131071, 8 elems each
        int kc  = tid >> 12;                 // k-chunk of 32, 0..31
        int nb  = (tid >> 6) & 63;           // n-block of 16
        int l   = tid & 63;                  // lane within fragment
        int n   = nb * 16 + (l & 15);
        int k   = kc * 32 + (l >> 4) * 8;
        const float* src = wo + (size_t)n * 1024 + k;
        float4 v0 = *(const float4*)(src);
        float4 v1 = *(const float4*)(src + 4);
        *(bf16x8*)(wob + (size_t)tid * 8) = cvt8(v0, v1);
    } else {
        int b = bid - 512;                  // 0..11
        int m = b >> 2;
        const float* src = (m == 0) ? wq : ((m == 1) ? wk : wv);
        int idx = ((b & 3) * 256 + threadIdx.x) * 4;
        float4 v = *(const float4*)(src + idx);
        uint2 p;
        p.x = pack2(v.x, v.y);
        p.y = pack2(v.z, v.w);
        *(uint2*)(wqkvb + m * 4096 + idx) = p;
    }
}

// ---------------------------------------------------------------------------
// K1 (MEGA): fused attention + output GEMM, SOFTWARE-PIPELINED PHASES.
// Identical to round 9 EXCEPT __launch_bounds__(512, 1).
// Round-9 forensics: (512,2) clamps the allocator to 128 VGPR (observed
// VGPR_Count=128 + ~76MB/dispatch scratch traffic = acc[4][8] spilled
// around each PAIR). LDS (144KB) already limits to 1 block/CU = 8 waves,
// so raising the VGPR cap to 256 costs zero occupancy. acc(128) + PAIR
// state(~110) ~= 240 should now stay resident.
//
// Pipeline: step p = { attention pair p || GEMM chunk p-1 }, opposite order
// for waves 0-3 vs 4-7 (w and w+4 share a SIMD -> each SIMD always hosts
// one MFMA-firing wave and one attention wave). Barrier per step orders
// pair-(p-1) writes before chunk-(p-1) reads; pair-p write stripes
// {2p,2p+1,8+2p,8+2p+1} disjoint from chunk-(p-1) read stripes. Final
// chunk(3) + epilogue after the loop. B-frag kc-stride = 32768 shorts
// (the round-9 fix, verified correct).
// ---------------------------------------------------------------------------
#define SCL 0.0450842200278f   /* log2(e)/32 */

#define MFMA_B16(A, B, Cc) __builtin_amdgcn_mfma_f32_16x16x32_bf16(A, B, Cc, 0, 0, 0)

__global__ __launch_bounds__(512, 1) void k_mega(const float* __restrict__ x,
                                                 const unsigned short* __restrict__ wqkv,
                                                 const unsigned short* __restrict__ wob,
                                                 const float* __restrict__ bias,
                                                 float* __restrict__ C) {
    extern __shared__ __align__(16) unsigned short lds[];
    unsigned short* out2s = lds;               // [64][1024] bf16 A-tile (128 KB)
    unsigned short* kscr  = lds + 65536;       // [8 waves][16][64] K-scratch (16 KB)

    const int t = threadIdx.x;
    const int w = t >> 6, l = t & 63;
    const int c = l & 15, q = l >> 4;
    const int bid   = blockIdx.x;
    const int batch = bid >> 3, q8r = bid & 7;
    unsigned short* kw = kscr + w * 1024;

    const int gbq = w >> 1;                    // wave-constant local group-block
    const int gc0 = (w & 1) * 8;               // wave's first column stripe

    // store masks for the 4 token-rows of a q-quadrant: rows 16q+gbq+4j
    const int mS0 = swz(16 * q + gbq);
    const int mS1 = swz(16 * q + gbq + 4);
    const int mS2 = swz(16 * q + gbq + 8);
    const int mS3 = swz(16 * q + gbq + 12);
    const int mkw = swz(c);                    // K-scratch read mask (row c)
    const int mqe = swz(c * 4 + gbq);          // energy Q-read mask (row 4c+gbq)
    const int mk0 = swz(4 * q);                // K-scratch write masks (rows 4q+j)
    const int mk1 = swz(4 * q + 1);
    const int mk2 = swz(4 * q + 2);
    const int mk3 = swz(4 * q + 3);

    const float* xb = x + ((size_t)bid * 1024 + c) * 64 + q * 8;
    const unsigned short* gBw = wob + (size_t)(w * 8) * 512 + (size_t)l * 8;

    f32x4 acc[4][8];
    #pragma unroll
    for (int m = 0; m < 4; ++m)
        #pragma unroll
        for (int nb = 0; nb < 8; ++nb)
            acc[m][nb] = (f32x4){0.f, 0.f, 0.f, 0.f};

    // ---- attention pair p: groups w*8 + 2p + {0,1} ----
    auto PAIR = [&](int p) {
        float4 xr[2][4];
        #pragma unroll
        for (int g = 0; g < 2; ++g) {
            const float* xp = xb + (size_t)(w * 8 + 2 * p + g) * 1024;
            xr[g][0] = *(const float4*)(xp);
            xr[g][1] = *(const float4*)(xp + 4);
            xr[g][2] = *(const float4*)(xp + 32);
            xr[g][3] = *(const float4*)(xp + 36);
        }
        bf16x8 xa[2][2];
        #pragma unroll
        for (int g = 0; g < 2; ++g) {
            xa[g][0] = cvt8(xr[g][0], xr[g][1]);
            xa[g][1] = cvt8(xr[g][2], xr[g][3]);
        }

        unsigned short* qs[2];
        qs[0] = out2s + (size_t)(16 * q + gbq) * 1024 + (gc0 + 2 * p) * 64;
        qs[1] = qs[0] + 64;

        // Q projection (both groups; W-frags shared)
        #pragma unroll
        for (int nb = 0; nb < 4; ++nb) {
            const unsigned short* wp = wqkv + (nb * 16 + c) * 64 + q * 8;
            bf16x8 w0 = *(const bf16x8*)(wp);
            bf16x8 w1 = *(const bf16x8*)(wp + 32);
            #pragma unroll
            for (int g = 0; g < 2; ++g) {
                f32x4 a2 = (f32x4){0.f, 0.f, 0.f, 0.f};
                a2 = MFMA_B16(xa[g][0], w0, a2);
                a2 = MFMA_B16(xa[g][1], w1, a2);
                unsigned u01 = pack2(a2[0], a2[1]);
                unsigned u23 = pack2(a2[2], a2[3]);
                const int d = nb * 16 + c;
                qs[g][(d ^ mS0)]             = (unsigned short)u01;
                qs[g][4 * 1024 + (d ^ mS1)]  = (unsigned short)(u01 >> 16);
                qs[g][8 * 1024 + (d ^ mS2)]  = (unsigned short)u23;
                qs[g][12 * 1024 + (d ^ mS3)] = (unsigned short)(u23 >> 16);
            }
        }

        // V projection (both groups) -> regs
        uint2 pkV[2][4];
        #pragma unroll
        for (int nb = 0; nb < 4; ++nb) {
            const unsigned short* wp = wqkv + 2 * 4096 + (nb * 16 + c) * 64 + q * 8;
            bf16x8 w0 = *(const bf16x8*)(wp);
            bf16x8 w1 = *(const bf16x8*)(wp + 32);
            #pragma unroll
            for (int g = 0; g < 2; ++g) {
                f32x4 a2 = (f32x4){0.f, 0.f, 0.f, 0.f};
                a2 = MFMA_B16(xa[g][0], w0, a2);
                a2 = MFMA_B16(xa[g][1], w1, a2);
                pkV[g][nb].x = pack2(a2[0], a2[1]);
                pkV[g][nb].y = pack2(a2[2], a2[3]);
            }
        }

        // K projection + energy, per group (shared kw scratch; same-wave DS order)
        f32x4 e[2];
        #pragma unroll
        for (int g = 0; g < 2; ++g) {
            #pragma unroll
            for (int nb = 0; nb < 4; ++nb) {
                const unsigned short* wp = wqkv + 4096 + (nb * 16 + c) * 64 + q * 8;
                bf16x8 w0 = *(const bf16x8*)(wp);
                bf16x8 w1 = *(const bf16x8*)(wp + 32);
                f32x4 a2 = (f32x4){0.f, 0.f, 0.f, 0.f};
                a2 = MFMA_B16(xa[g][0], w0, a2);
                a2 = MFMA_B16(xa[g][1], w1, a2);
                unsigned u01 = pack2(a2[0], a2[1]);
                unsigned u23 = pack2(a2[2], a2[3]);
                const int d = nb * 16 + c;
                const int kr = 4 * q;
                kw[(kr + 0) * 64 + (d ^ mk0)] = (unsigned short)u01;
                kw[(kr + 1) * 64 + (d ^ mk1)] = (unsigned short)(u01 >> 16);
                kw[(kr + 2) * 64 + (d ^ mk2)] = (unsigned short)u23;
                kw[(kr + 3) * 64 + (d ^ mk3)] = (unsigned short)(u23 >> 16);
            }
            e[g] = (f32x4){0.f, 0.f, 0.f, 0.f};
            const unsigned short* qrow = out2s + (size_t)(c * 4 + gbq) * 1024
                                               + (gc0 + 2 * p + g) * 64;
            #pragma unroll
            for (int kc2 = 0; kc2 < 2; ++kc2) {
                const int L = kc2 * 32 + q * 8;
                bf16x8 ka = *(const bf16x8*)(kw + c * 64 + (L ^ mkw));
                bf16x8 qb = *(const bf16x8*)(qrow + (L ^ mqe));
                e[g] = MFMA_B16(ka, qb, e[g]);
            }
        }

        // softmax (both groups)
        unsigned pa0[2], pa1[2];
        #pragma unroll
        for (int g = 0; g < 2; ++g) {
            float mx = fmaxf(fmaxf(e[g][0], e[g][1]), fmaxf(e[g][2], e[g][3]));
            mx = fmaxf(mx, __shfl_xor(mx, 16));
            mx = fmaxf(mx, __shfl_xor(mx, 32));
            float p0 = exp2f((e[g][0] - mx) * SCL);
            float p1 = exp2f((e[g][1] - mx) * SCL);
            float p2 = exp2f((e[g][2] - mx) * SCL);
            float p3 = exp2f((e[g][3] - mx) * SCL);
            float s = p0 + p1 + p2 + p3;
            s += __shfl_xor(s, 16);
            s += __shfl_xor(s, 32);
            float rinv = 1.0f / s;
            pa0[g] = pack2(p0 * rinv, p1 * rinv);   // j = 4q+0,1
            pa1[g] = pack2(p2 * rinv, p3 * rinv);   // j = 4q+2,3
        }

        // PV (both groups); output overwrites the Q stripe
        const int sh0 = (32 * q + c) & 63;
        const int sh1 = (32 * q + 16 + c) & 63;
        const int sv0 = 32 * (q & 1) + c;
        const int sv1 = sv0 + 16;
        const bool hi = (q >= 2);                   // k >= 16 -> zero pad
        #pragma unroll
        for (int g = 0; g < 2; ++g) {
            int a0 = __shfl((int)pa0[g], sh0);
            int a1 = __shfl((int)pa1[g], sh0);
            int a2 = __shfl((int)pa0[g], sh1);
            int a3 = __shfl((int)pa1[g], sh1);
            uint4 A2u;
            A2u.x = hi ? 0u : (unsigned)a0;
            A2u.y = hi ? 0u : (unsigned)a1;
            A2u.z = hi ? 0u : (unsigned)a2;
            A2u.w = hi ? 0u : (unsigned)a3;
            bf16x8 A2 = __builtin_bit_cast(bf16x8, A2u);

            #pragma unroll
            for (int nb = 0; nb < 4; ++nb) {
                uint4 B2u;
                B2u.x = (unsigned)__shfl((int)pkV[g][nb].x, sv0);
                B2u.y = (unsigned)__shfl((int)pkV[g][nb].y, sv0);
                B2u.z = (unsigned)__shfl((int)pkV[g][nb].x, sv1);
                B2u.w = (unsigned)__shfl((int)pkV[g][nb].y, sv1);
                bf16x8 B2 = __builtin_bit_cast(bf16x8, B2u);
                f32x4 o = (f32x4){0.f, 0.f, 0.f, 0.f};
                o = MFMA_B16(A2, B2, o);
                unsigned u01 = pack2(o[0], o[1]);
                unsigned u23 = pack2(o[2], o[3]);
                const int d = nb * 16 + c;
                qs[g][(d ^ mS0)]             = (unsigned short)u01;
                qs[g][4 * 1024 + (d ^ mS1)]  = (unsigned short)(u01 >> 16);
                qs[g][8 * 1024 + (d ^ mS2)]  = (unsigned short)u23;
                qs[g][12 * 1024 + (d ^ mS3)] = (unsigned short)(u23 >> 16);
            }
        }
    };

    // ---- GEMM chunk for pair cp: kc in {4cp..4cp+3} u {16+4cp..16+4cp+3} ----
    // B-frag address = gBw + kc*32768 + nb*512  (64 frags x 512 per kc slice).
    auto CHUNK = [&](int cp) {
        #pragma unroll
        for (int h = 0; h < 2; ++h) {
            #pragma unroll
            for (int kk = 0; kk < 4; ++kk) {
                const int kc = h * 16 + 4 * cp + kk;
                bf16x8 bb[8];
                #pragma unroll
                for (int nb = 0; nb < 8; ++nb)
                    bb[nb] = *(const bf16x8*)(gBw + (size_t)kc * 32768 + nb * 512);
                const int L = kc * 32 + q * 8;
                bf16x8 av[4];
                #pragma unroll
                for (int m = 0; m < 4; ++m)
                    av[m] = *(const bf16x8*)(out2s + (size_t)(m * 16 + c) * 1024
                                                   + (L ^ swz(m * 16 + c)));
                #pragma unroll
                for (int m = 0; m < 4; ++m)
                    #pragma unroll
                    for (int nb = 0; nb < 8; ++nb)
                        acc[m][nb] = MFMA_B16(av[m], bb[nb], acc[m][nb]);
            }
        }
    };

    // ---- pipelined steps: attention pair p || GEMM chunk p-1 ----
    // waves 0-3 and 4-7 run the two halves in opposite order; w and w+4
    // share a SIMD, so each SIMD always has one MFMA wave + one attn wave.
    #pragma unroll 1
    for (int p = 0; p < 4; ++p) {
        __syncthreads();   // pair p-1 writes complete before chunk p-1 reads
        if (w >= 4) {
            if (p > 0) CHUNK(p - 1);
            PAIR(p);
        } else {
            PAIR(p);
            if (p > 0) CHUNK(p - 1);
        }
    }
    __syncthreads();
    CHUNK(3);

    // ---- epilogue: bias + fp32 store. Local row lr = m*16 + q*4 + r:
    //      rg = batch*512 + (4m+q)*32 + (bid&7)*4 + r.
    float bc[8];
    #pragma unroll
    for (int nb = 0; nb < 8; ++nb) bc[nb] = bias[w * 128 + nb * 16 + c];
    #pragma unroll
    for (int m = 0; m < 4; ++m) {
        #pragma unroll
        for (int r = 0; r < 4; ++r) {
            const int rg = batch * 512 + (m * 4 + q) * 32 + q8r * 4 + r;
            float* cp2 = C + (size_t)rg * 1024 + w * 128 + c;
            #pragma unroll
            for (int nb = 0; nb < 8; ++nb)
                cp2[nb * 16] = acc[m][nb][r] + bc[nb];
        }
    }
}

// ---------------------------------------------------------------------------
extern "C" void kernel_launch(void* const* d_in, const int* in_sizes, int n_in,
                              void* d_out, int out_size, void* d_ws, size_t ws_size,
                              hipStream_t stream) {
    const float* x  = (const float*)d_in[0];
    const float* wq = (const float*)d_in[1];
    const float* wk = (const float*)d_in[2];
    const float* wv = (const float*)d_in[3];
    const float* wo = (const float*)d_in[4];
    const float* bo = (const float*)d_in[5];
    float* out = (float*)d_out;

    unsigned short* wob   = (unsigned short*)d_ws;           // 1024*1024 bf16 packed (2 MB)
    unsigned short* wqkvb = wob + (size_t)EMB * EMB;         // 3*4096 bf16 (24 KB)

    static int s_once = []() {
        hipFuncSetAttribute((const void*)k_mega,
                            hipFuncAttributeMaxDynamicSharedMemorySize, 147456);
        return 0;
    }();
    (void)s_once;

    k_cvt <<<524, 256, 0, stream>>>(wo, wq, wk, wv, wob, wqkvb);
    k_mega<<<256, 512, 147456, stream>>>(x, wqkvb, wob, bo, out);
}

// Round 12
// 206.745 us; speedup vs baseline: 1.0046x; 1.0042x over previous
//
#include <hip/hip_runtime.h>
#include <hip/hip_bf16.h>
#include <stdint.h>

// Problem constants
#define TOKS   262144      // B*S = 32*8192
#define NGRP   16384       // B*G = 32*512
#define EMB    1024
#define HD     64

using bf16x8 = __attribute__((ext_vector_type(8))) short;   // 8 bf16 (4 VGPRs) MFMA operand
using f32x4  = __attribute__((ext_vector_type(4))) float;   // MFMA accumulator

__device__ __forceinline__ unsigned pack2(float a, float b) {
    union { __hip_bfloat162 h; unsigned u; } cvt;
    cvt.h = __float22bfloat162_rn(make_float2(a, b));   // RNE pk-convert
    return cvt.u;
}
__device__ __forceinline__ bf16x8 cvt8(float4 v0, float4 v1) {
    uint4 u;
    u.x = pack2(v0.x, v0.y);
    u.y = pack2(v0.z, v0.w);
    u.z = pack2(v1.x, v1.y);
    u.w = pack2(v1.z, v1.w);
    return __builtin_bit_cast(bf16x8, u);
}
// 3-term row swizzle: 16B-chunk XOR mask within each 128B (64-el) stripe.
__device__ __forceinline__ int swz(int r) {
    return ((r ^ (r >> 2) ^ (r >> 4)) & 7) << 3;
}

// ---------------------------------------------------------------------------
// K0: pack Wo (fp32 [1024][1024]) into MFMA-fragment-linear bf16 (blocks 0..511):
//       packed[((kc*64 + nb)*64 + l)*8 + e] = bf16(Wo[nb*16 + (l&15)][kc*32 + (l>>4)*8 + e])
//     Wq|Wk|Wv (fp32 [64][64]) -> bf16 packed [3][4096] (blocks 512..523).
// ---------------------------------------------------------------------------
__global__ __launch_bounds__(256) void k_cvt(const float* __restrict__ wo,
                                             const float* __restrict__ wq,
                                             const float* __restrict__ wk,
                                             const float* __restrict__ wv,
                                             unsigned short* __restrict__ wob,
                                             unsigned short* __restrict__ wqkvb) {
    int bid = blockIdx.x;
    if (bid < 512) {
        int tid = bid * 256 + threadIdx.x;   // 0..131071, 8 elems each
        int kc  = tid >> 12;                 // k-chunk of 32, 0..31
        int nb  = (tid >> 6) & 63;           // n-block of 16
        int l   = tid & 63;                  // lane within fragment
        int n   = nb * 16 + (l & 15);
        int k   = kc * 32 + (l >> 4) * 8;
        const float* src = wo + (size_t)n * 1024 + k;
        float4 v0 = *(const float4*)(src);
        float4 v1 = *(const float4*)(src + 4);
        *(bf16x8*)(wob + (size_t)tid * 8) = cvt8(v0, v1);
    } else {
        int b = bid - 512;                  // 0..11
        int m = b >> 2;
        const float* src = (m == 0) ? wq : ((m == 1) ? wk : wv);
        int idx = ((b & 3) * 256 + threadIdx.x) * 4;
        float4 v = *(const float4*)(src + idx);
        uint2 p;
        p.x = pack2(v.x, v.y);
        p.y = pack2(v.z, v.w);
        *(uint2*)(wqkvb + m * 4096 + idx) = p;
    }
}

// ---------------------------------------------------------------------------
// K1 (MEGA): fused attention + output GEMM, SOFTWARE-PIPELINED PHASES.
// (Round 12 = round 11 resubmitted verbatim — round 11 hit an infra
// failure, the experiment never executed.)
// Round-10 forensics: VGPR_Count stayed 128 with both (512,2) and (512,1) —
// the LDS is dynamic, so the RA cannot see that 144KB forces 1 block/CU
// (2 waves/SIMD) and targets a default 4-waves/SIMD occupancy (<=128 VGPR),
// spilling acc[4][8] (~77MB/dispatch scratch traffic, 115us). Fix:
// __attribute__((amdgpu_waves_per_eu(1, 2))) — the max=2 tells the RA that
// occupancy cannot exceed 2 waves/EU anyway, so up to 256 VGPRs are free.
// launch_bounds kept single-arg to avoid a duplicate waves_per_eu attr.
//
// Pipeline: step p = { attention pair p || GEMM chunk p-1 }, opposite order
// for waves 0-3 vs 4-7 (w and w+4 share a SIMD -> each SIMD always hosts
// one MFMA-firing wave and one attention wave). Barrier per step orders
// pair-(p-1) writes before chunk-(p-1) reads; pair-p write stripes
// {2p,2p+1,8+2p,8+2p+1} disjoint from chunk-(p-1) read stripes. Final
// chunk(3) + epilogue after the loop. B-frag kc-stride = 32768 shorts
// (round-9 fix, verified correct).
// ---------------------------------------------------------------------------
#define SCL 0.0450842200278f   /* log2(e)/32 */

#define MFMA_B16(A, B, Cc) __builtin_amdgcn_mfma_f32_16x16x32_bf16(A, B, Cc, 0, 0, 0)

__global__ __launch_bounds__(512)
__attribute__((amdgpu_waves_per_eu(1, 2)))
void k_mega(const float* __restrict__ x,
            const unsigned short* __restrict__ wqkv,
            const unsigned short* __restrict__ wob,
            const float* __restrict__ bias,
            float* __restrict__ C) {
    extern __shared__ __align__(16) unsigned short lds[];
    unsigned short* out2s = lds;               // [64][1024] bf16 A-tile (128 KB)
    unsigned short* kscr  = lds + 65536;       // [8 waves][16][64] K-scratch (16 KB)

    const int t = threadIdx.x;
    const int w = t >> 6, l = t & 63;
    const int c = l & 15, q = l >> 4;
    const int bid   = blockIdx.x;
    const int batch = bid >> 3, q8r = bid & 7;
    unsigned short* kw = kscr + w * 1024;

    const int gbq = w >> 1;                    // wave-constant local group-block
    const int gc0 = (w & 1) * 8;               // wave's first column stripe

    // store masks for the 4 token-rows of a q-quadrant: rows 16q+gbq+4j
    const int mS0 = swz(16 * q + gbq);
    const int mS1 = swz(16 * q + gbq + 4);
    const int mS2 = swz(16 * q + gbq + 8);
    const int mS3 = swz(16 * q + gbq + 12);
    const int mkw = swz(c);                    // K-scratch read mask (row c)
    const int mqe = swz(c * 4 + gbq);          // energy Q-read mask (row 4c+gbq)
    const int mk0 = swz(4 * q);                // K-scratch write masks (rows 4q+j)
    const int mk1 = swz(4 * q + 1);
    const int mk2 = swz(4 * q + 2);
    const int mk3 = swz(4 * q + 3);

    const float* xb = x + ((size_t)bid * 1024 + c) * 64 + q * 8;
    const unsigned short* gBw = wob + (size_t)(w * 8) * 512 + (size_t)l * 8;

    f32x4 acc[4][8];
    #pragma unroll
    for (int m = 0; m < 4; ++m)
        #pragma unroll
        for (int nb = 0; nb < 8; ++nb)
            acc[m][nb] = (f32x4){0.f, 0.f, 0.f, 0.f};

    // ---- attention pair p: groups w*8 + 2p + {0,1} ----
    auto PAIR = [&](int p) {
        float4 xr[2][4];
        #pragma unroll
        for (int g = 0; g < 2; ++g) {
            const float* xp = xb + (size_t)(w * 8 + 2 * p + g) * 1024;
            xr[g][0] = *(const float4*)(xp);
            xr[g][1] = *(const float4*)(xp + 4);
            xr[g][2] = *(const float4*)(xp + 32);
            xr[g][3] = *(const float4*)(xp + 36);
        }
        bf16x8 xa[2][2];
        #pragma unroll
        for (int g = 0; g < 2; ++g) {
            xa[g][0] = cvt8(xr[g][0], xr[g][1]);
            xa[g][1] = cvt8(xr[g][2], xr[g][3]);
        }

        unsigned short* qs[2];
        qs[0] = out2s + (size_t)(16 * q + gbq) * 1024 + (gc0 + 2 * p) * 64;
        qs[1] = qs[0] + 64;

        // Q projection (both groups; W-frags shared)
        #pragma unroll
        for (int nb = 0; nb < 4; ++nb) {
            const unsigned short* wp = wqkv + (nb * 16 + c) * 64 + q * 8;
            bf16x8 w0 = *(const bf16x8*)(wp);
            bf16x8 w1 = *(const bf16x8*)(wp + 32);
            #pragma unroll
            for (int g = 0; g < 2; ++g) {
                f32x4 a2 = (f32x4){0.f, 0.f, 0.f, 0.f};
                a2 = MFMA_B16(xa[g][0], w0, a2);
                a2 = MFMA_B16(xa[g][1], w1, a2);
                unsigned u01 = pack2(a2[0], a2[1]);
                unsigned u23 = pack2(a2[2], a2[3]);
                const int d = nb * 16 + c;
                qs[g][(d ^ mS0)]             = (unsigned short)u01;
                qs[g][4 * 1024 + (d ^ mS1)]  = (unsigned short)(u01 >> 16);
                qs[g][8 * 1024 + (d ^ mS2)]  = (unsigned short)u23;
                qs[g][12 * 1024 + (d ^ mS3)] = (unsigned short)(u23 >> 16);
            }
        }

        // V projection (both groups) -> regs
        uint2 pkV[2][4];
        #pragma unroll
        for (int nb = 0; nb < 4; ++nb) {
            const unsigned short* wp = wqkv + 2 * 4096 + (nb * 16 + c) * 64 + q * 8;
            bf16x8 w0 = *(const bf16x8*)(wp);
            bf16x8 w1 = *(const bf16x8*)(wp + 32);
            #pragma unroll
            for (int g = 0; g < 2; ++g) {
                f32x4 a2 = (f32x4){0.f, 0.f, 0.f, 0.f};
                a2 = MFMA_B16(xa[g][0], w0, a2);
                a2 = MFMA_B16(xa[g][1], w1, a2);
                pkV[g][nb].x = pack2(a2[0], a2[1]);
                pkV[g][nb].y = pack2(a2[2], a2[3]);
            }
        }

        // K projection + energy, per group (shared kw scratch; same-wave DS order)
        f32x4 e[2];
        #pragma unroll
        for (int g = 0; g < 2; ++g) {
            #pragma unroll
            for (int nb = 0; nb < 4; ++nb) {
                const unsigned short* wp = wqkv + 4096 + (nb * 16 + c) * 64 + q * 8;
                bf16x8 w0 = *(const bf16x8*)(wp);
                bf16x8 w1 = *(const bf16x8*)(wp + 32);
                f32x4 a2 = (f32x4){0.f, 0.f, 0.f, 0.f};
                a2 = MFMA_B16(xa[g][0], w0, a2);
                a2 = MFMA_B16(xa[g][1], w1, a2);
                unsigned u01 = pack2(a2[0], a2[1]);
                unsigned u23 = pack2(a2[2], a2[3]);
                const int d = nb * 16 + c;
                const int kr = 4 * q;
                kw[(kr + 0) * 64 + (d ^ mk0)] = (unsigned short)u01;
                kw[(kr + 1) * 64 + (d ^ mk1)] = (unsigned short)(u01 >> 16);
                kw[(kr + 2) * 64 + (d ^ mk2)] = (unsigned short)u23;
                kw[(kr + 3) * 64 + (d ^ mk3)] = (unsigned short)(u23 >> 16);
            }
            e[g] = (f32x4){0.f, 0.f, 0.f, 0.f};
            const unsigned short* qrow = out2s + (size_t)(c * 4 + gbq) * 1024
                                               + (gc0 + 2 * p + g) * 64;
            #pragma unroll
            for (int kc2 = 0; kc2 < 2; ++kc2) {
                const int L = kc2 * 32 + q * 8;
                bf16x8 ka = *(const bf16x8*)(kw + c * 64 + (L ^ mkw));
                bf16x8 qb = *(const bf16x8*)(qrow + (L ^ mqe));
                e[g] = MFMA_B16(ka, qb, e[g]);
            }
        }

        // softmax (both groups)
        unsigned pa0[2], pa1[2];
        #pragma unroll
        for (int g = 0; g < 2; ++g) {
            float mx = fmaxf(fmaxf(e[g][0], e[g][1]), fmaxf(e[g][2], e[g][3]));
            mx = fmaxf(mx, __shfl_xor(mx, 16));
            mx = fmaxf(mx, __shfl_xor(mx, 32));
            float p0 = exp2f((e[g][0] - mx) * SCL);
            float p1 = exp2f((e[g][1] - mx) * SCL);
            float p2 = exp2f((e[g][2] - mx) * SCL);
            float p3 = exp2f((e[g][3] - mx) * SCL);
            float s = p0 + p1 + p2 + p3;
            s += __shfl_xor(s, 16);
            s += __shfl_xor(s, 32);
            float rinv = 1.0f / s;
            pa0[g] = pack2(p0 * rinv, p1 * rinv);   // j = 4q+0,1
            pa1[g] = pack2(p2 * rinv, p3 * rinv);   // j = 4q+2,3
        }

        // PV (both groups); output overwrites the Q stripe
        const int sh0 = (32 * q + c) & 63;
        const int sh1 = (32 * q + 16 + c) & 63;
        const int sv0 = 32 * (q & 1) + c;
        const int sv1 = sv0 + 16;
        const bool hi = (q >= 2);                   // k >= 16 -> zero pad
        #pragma unroll
        for (int g = 0; g < 2; ++g) {
            int a0 = __shfl((int)pa0[g], sh0);
            int a1 = __shfl((int)pa1[g], sh0);
            int a2 = __shfl((int)pa0[g], sh1);
            int a3 = __shfl((int)pa1[g], sh1);
            uint4 A2u;
            A2u.x = hi ? 0u : (unsigned)a0;
            A2u.y = hi ? 0u : (unsigned)a1;
            A2u.z = hi ? 0u : (unsigned)a2;
            A2u.w = hi ? 0u : (unsigned)a3;
            bf16x8 A2 = __builtin_bit_cast(bf16x8, A2u);

            #pragma unroll
            for (int nb = 0; nb < 4; ++nb) {
                uint4 B2u;
                B2u.x = (unsigned)__shfl((int)pkV[g][nb].x, sv0);
                B2u.y = (unsigned)__shfl((int)pkV[g][nb].y, sv0);
                B2u.z = (unsigned)__shfl((int)pkV[g][nb].x, sv1);
                B2u.w = (unsigned)__shfl((int)pkV[g][nb].y, sv1);
                bf16x8 B2 = __builtin_bit_cast(bf16x8, B2u);
                f32x4 o = (f32x4){0.f, 0.f, 0.f, 0.f};
                o = MFMA_B16(A2, B2, o);
                unsigned u01 = pack2(o[0], o[1]);
                unsigned u23 = pack2(o[2], o[3]);
                const int d = nb * 16 + c;
                qs[g][(d ^ mS0)]             = (unsigned short)u01;
                qs[g][4 * 1024 + (d ^ mS1)]  = (unsigned short)(u01 >> 16);
                qs[g][8 * 1024 + (d ^ mS2)]  = (unsigned short)u23;
                qs[g][12 * 1024 + (d ^ mS3)] = (unsigned short)(u23 >> 16);
            }
        }
    };

    // ---- GEMM chunk for pair cp: kc in {4cp..4cp+3} u {16+4cp..16+4cp+3} ----
    // B-frag address = gBw + kc*32768 + nb*512  (64 frags x 512 per kc slice).
    auto CHUNK = [&](int cp) {
        #pragma unroll
        for (int h = 0; h < 2; ++h) {
            #pragma unroll
            for (int kk = 0; kk < 4; ++kk) {
                const int kc = h * 16 + 4 * cp + kk;
                bf16x8 bb[8];
                #pragma unroll
                for (int nb = 0; nb < 8; ++nb)
                    bb[nb] = *(const bf16x8*)(gBw + (size_t)kc * 32768 + nb * 512);
                const int L = kc * 32 + q * 8;
                bf16x8 av[4];
                #pragma unroll
                for (int m = 0; m < 4; ++m)
                    av[m] = *(const bf16x8*)(out2s + (size_t)(m * 16 + c) * 1024
                                                   + (L ^ swz(m * 16 + c)));
                #pragma unroll
                for (int m = 0; m < 4; ++m)
                    #pragma unroll
                    for (int nb = 0; nb < 8; ++nb)
                        acc[m][nb] = MFMA_B16(av[m], bb[nb], acc[m][nb]);
            }
        }
    };

    // ---- pipelined steps: attention pair p || GEMM chunk p-1 ----
    // waves 0-3 and 4-7 run the two halves in opposite order; w and w+4
    // share a SIMD, so each SIMD always has one MFMA wave + one attn wave.
    #pragma unroll 1
    for (int p = 0; p < 4; ++p) {
        __syncthreads();   // pair p-1 writes complete before chunk p-1 reads
        if (w >= 4) {
            if (p > 0) CHUNK(p - 1);
            PAIR(p);
        } else {
            PAIR(p);
            if (p > 0) CHUNK(p - 1);
        }
    }
    __syncthreads();
    CHUNK(3);

    // ---- epilogue: bias + fp32 store. Local row lr = m*16 + q*4 + r:
    //      rg = batch*512 + (4m+q)*32 + (bid&7)*4 + r.
    float bc[8];
    #pragma unroll
    for (int nb = 0; nb < 8; ++nb) bc[nb] = bias[w * 128 + nb * 16 + c];
    #pragma unroll
    for (int m = 0; m < 4; ++m) {
        #pragma unroll
        for (int r = 0; r < 4; ++r) {
            const int rg = batch * 512 + (m * 4 + q) * 32 + q8r * 4 + r;
            float* cp2 = C + (size_t)rg * 1024 + w * 128 + c;
            #pragma unroll
            for (int nb = 0; nb < 8; ++nb)
                cp2[nb * 16] = acc[m][nb][r] + bc[nb];
        }
    }
}

// ---------------------------------------------------------------------------
extern "C" void kernel_launch(void* const* d_in, const int* in_sizes, int n_in,
                              void* d_out, int out_size, void* d_ws, size_t ws_size,
                              hipStream_t stream) {
    const float* x  = (const float*)d_in[0];
    const float* wq = (const float*)d_in[1];
    const float* wk = (const float*)d_in[2];
    const float* wv = (const float*)d_in[3];
    const float* wo = (const float*)d_in[4];
    const float* bo = (const float*)d_in[5];
    float* out = (float*)d_out;

    unsigned short* wob   = (unsigned short*)d_ws;           // 1024*1024 bf16 packed (2 MB)
    unsigned short* wqkvb = wob + (size_t)EMB * EMB;         // 3*4096 bf16 (24 KB)

    static int s_once = []() {
        hipFuncSetAttribute((const void*)k_mega,
                            hipFuncAttributeMaxDynamicSharedMemorySize, 147456);
        return 0;
    }();
    (void)s_once;

    k_cvt <<<524, 256, 0, stream>>>(wo, wq, wk, wv, wob, wqkvb);
    k_mega<<<256, 512, 147456, stream>>>(x, wqkvb, wob, bo, out);
}

// Round 13
// 175.171 us; speedup vs baseline: 1.1857x; 1.1802x over previous
//
#include <hip/hip_runtime.h>
#include <hip/hip_bf16.h>
#include <stdint.h>

// Problem constants
#define TOKS   262144      // B*S = 32*8192
#define NGRP   16384       // B*G = 32*512
#define EMB    1024
#define HD     64

using bf16x8 = __attribute__((ext_vector_type(8))) short;   // 8 bf16 (4 VGPRs) MFMA operand
using f32x4  = __attribute__((ext_vector_type(4))) float;   // MFMA accumulator

__device__ __forceinline__ unsigned pack2(float a, float b) {
    union { __hip_bfloat162 h; unsigned u; } cvt;
    cvt.h = __float22bfloat162_rn(make_float2(a, b));   // RNE pk-convert
    return cvt.u;
}
__device__ __forceinline__ bf16x8 cvt8(float4 v0, float4 v1) {
    uint4 u;
    u.x = pack2(v0.x, v0.y);
    u.y = pack2(v0.z, v0.w);
    u.z = pack2(v1.x, v1.y);
    u.w = pack2(v1.z, v1.w);
    return __builtin_bit_cast(bf16x8, u);
}
// 3-term row swizzle: 16B-chunk XOR mask within each 128B (64-el) stripe.
__device__ __forceinline__ int swz(int r) {
    return ((r ^ (r >> 2) ^ (r >> 4)) & 7) << 3;
}

// ---------------------------------------------------------------------------
// K0: pack Wo (fp32 [1024][1024]) into MFMA-fragment-linear bf16 (blocks 0..511):
//       packed[((kc*64 + nb)*64 + l)*8 + e] = bf16(Wo[nb*16 + (l&15)][kc*32 + (l>>4)*8 + e])
//     Wq|Wk|Wv (fp32 [64][64]) -> bf16 packed [3][4096] (blocks 512..523).
// ---------------------------------------------------------------------------
__global__ __launch_bounds__(256) void k_cvt(const float* __restrict__ wo,
                                             const float* __restrict__ wq,
                                             const float* __restrict__ wk,
                                             const float* __restrict__ wv,
                                             unsigned short* __restrict__ wob,
                                             unsigned short* __restrict__ wqkvb) {
    int bid = blockIdx.x;
    if (bid < 512) {
        int tid = bid * 256 + threadIdx.x;   // 0..131071, 8 elems each
        int kc  = tid >> 12;                 // k-chunk of 32, 0..31
        int nb  = (tid >> 6) & 63;           // n-block of 16
        int l   = tid & 63;                  // lane within fragment
        int n   = nb * 16 + (l & 15);
        int k   = kc * 32 + (l >> 4) * 8;
        const float* src = wo + (size_t)n * 1024 + k;
        float4 v0 = *(const float4*)(src);
        float4 v1 = *(const float4*)(src + 4);
        *(bf16x8*)(wob + (size_t)tid * 8) = cvt8(v0, v1);
    } else {
        int b = bid - 512;                  // 0..11
        int m = b >> 2;
        const float* src = (m == 0) ? wq : ((m == 1) ? wk : wv);
        int idx = ((b & 3) * 256 + threadIdx.x) * 4;
        float4 v = *(const float4*)(src + idx);
        uint2 p;
        p.x = pack2(v.x, v.y);
        p.y = pack2(v.z, v.w);
        *(uint2*)(wqkvb + m * 4096 + idx) = p;
    }
}

// ---------------------------------------------------------------------------
// K1 (MEGA, half-block): fused attention + output GEMM, serial phases,
// 2 BLOCKS/CU. Rounds 8-12 proved the in-wave pipelined variant is dead:
// the RA refuses >128 VGPR for this kernel (three mechanisms tried), and
// acc+attention state need ~205. This variant gets the same overlap from
// CO-RESIDENT BLOCKS instead: block = 512 tokens / 32 groups / 32 out2
// rows -> A-tile 64KB + kscr 16KB = exactly 80KB LDS -> 2 blocks/CU
// (160KB exact). Grid 512 = 2/CU.
//   (a) attention now runs at 4 waves/SIMD (2x TLP for the latency chain);
//   (b) desynced co-resident blocks put one block's GEMM (MFMA + L2
//       B-stream) under the other's attention (VALU/DS/latency);
//   (c) no register co-residency: attention peak ~116, GEMM peak ~100,
//       both under the 128 cap -> no spills (tripwire: WRITE == 65.5MB).
// Row map: out2 row (per batch) = head*32 + (g>>4). Block bid = batch*16+h16
// owns groups grem = h16*32 + gl (gl 0..31) -> rows {2*h16 + e + 32*head},
// local row lr = e + 2*head, e = gl>>4 = w>>2. Wave w: 4 groups gl = w*4+i,
// col stripes (w&3)*4+i. GEMM: per wave 32 rows x 128 cols, acc[2][8],
// kc ascending (accumulation order identical to rounds 2-7).
// ---------------------------------------------------------------------------
#define SCL 0.0450842200278f   /* log2(e)/32 */

#define MFMA_B16(A, B, Cc) __builtin_amdgcn_mfma_f32_16x16x32_bf16(A, B, Cc, 0, 0, 0)

__global__ __launch_bounds__(512) void k_mega(const float* __restrict__ x,
                                              const unsigned short* __restrict__ wqkv,
                                              const unsigned short* __restrict__ wob,
                                              const float* __restrict__ bias,
                                              float* __restrict__ C) {
    extern __shared__ __align__(16) unsigned short lds[];
    unsigned short* out2s = lds;               // [32][1024] bf16 A-tile (64 KB)
    unsigned short* kscr  = lds + 32768;       // [8 waves][16][64] K-scratch (16 KB)

    const int t = threadIdx.x;
    const int w = t >> 6, l = t & 63;
    const int c = l & 15, q = l >> 4;
    const int bid   = blockIdx.x;
    const int batch = bid >> 4, h16 = bid & 15;
    unsigned short* kw = kscr + w * 1024;

    const int e   = w >> 2;                    // wave-constant row parity
    const int gc0 = (w & 3) * 4;               // wave's first column stripe

    // store masks for the 4 token-rows of a q-quadrant: rows 8q+e+2r
    const int mS0 = swz(8 * q + e);
    const int mS1 = swz(8 * q + e + 2);
    const int mS2 = swz(8 * q + e + 4);
    const int mS3 = swz(8 * q + e + 6);
    const int mkw = swz(c);                    // K-scratch read mask (row c)
    const int mqe = swz(2 * c + e);            // energy Q-read mask (row 2c+e)
    const int mk0 = swz(4 * q);                // K-scratch write masks (rows 4q+j)
    const int mk1 = swz(4 * q + 1);
    const int mk2 = swz(4 * q + 2);
    const int mk3 = swz(4 * q + 3);

    const float* xb = x + ((size_t)bid * 512 + c) * 64 + q * 8;

    // ================= phase 1: attention, 2 interleaved pairs ============
    #pragma unroll 1
    for (int p = 0; p < 2; ++p) {
        // groups gl = w*4 + 2p + {0,1}
        float4 xr[2][4];
        #pragma unroll
        for (int g = 0; g < 2; ++g) {
            const float* xp = xb + (size_t)(w * 4 + 2 * p + g) * 1024;
            xr[g][0] = *(const float4*)(xp);
            xr[g][1] = *(const float4*)(xp + 4);
            xr[g][2] = *(const float4*)(xp + 32);
            xr[g][3] = *(const float4*)(xp + 36);
        }
        bf16x8 xa[2][2];
        #pragma unroll
        for (int g = 0; g < 2; ++g) {
            xa[g][0] = cvt8(xr[g][0], xr[g][1]);
            xa[g][1] = cvt8(xr[g][2], xr[g][3]);
        }

        // Q/O slot: rows 8q+e (+2 per r), column stripe gc0+2p+g
        unsigned short* qs[2];
        qs[0] = out2s + (size_t)(8 * q + e) * 1024 + (gc0 + 2 * p) * 64;
        qs[1] = qs[0] + 64;

        // ---- Q projection (both groups; W-frags shared) ----
        #pragma unroll
        for (int nb = 0; nb < 4; ++nb) {
            const unsigned short* wp = wqkv + (nb * 16 + c) * 64 + q * 8;
            bf16x8 w0 = *(const bf16x8*)(wp);
            bf16x8 w1 = *(const bf16x8*)(wp + 32);
            #pragma unroll
            for (int g = 0; g < 2; ++g) {
                f32x4 a2 = (f32x4){0.f, 0.f, 0.f, 0.f};
                a2 = MFMA_B16(xa[g][0], w0, a2);
                a2 = MFMA_B16(xa[g][1], w1, a2);
                unsigned u01 = pack2(a2[0], a2[1]);
                unsigned u23 = pack2(a2[2], a2[3]);
                const int d = nb * 16 + c;
                qs[g][(d ^ mS0)]            = (unsigned short)u01;
                qs[g][2048 + (d ^ mS1)]     = (unsigned short)(u01 >> 16);
                qs[g][4096 + (d ^ mS2)]     = (unsigned short)u23;
                qs[g][6144 + (d ^ mS3)]     = (unsigned short)(u23 >> 16);
            }
        }

        // ---- V projection (both groups) -> regs ----
        uint2 pkV[2][4];
        #pragma unroll
        for (int nb = 0; nb < 4; ++nb) {
            const unsigned short* wp = wqkv + 2 * 4096 + (nb * 16 + c) * 64 + q * 8;
            bf16x8 w0 = *(const bf16x8*)(wp);
            bf16x8 w1 = *(const bf16x8*)(wp + 32);
            #pragma unroll
            for (int g = 0; g < 2; ++g) {
                f32x4 a2 = (f32x4){0.f, 0.f, 0.f, 0.f};
                a2 = MFMA_B16(xa[g][0], w0, a2);
                a2 = MFMA_B16(xa[g][1], w1, a2);
                pkV[g][nb].x = pack2(a2[0], a2[1]);
                pkV[g][nb].y = pack2(a2[2], a2[3]);
            }
        }

        // ---- K projection + energy, per group (shared kw; same-wave DS order)
        f32x4 en[2];
        #pragma unroll
        for (int g = 0; g < 2; ++g) {
            #pragma unroll
            for (int nb = 0; nb < 4; ++nb) {
                const unsigned short* wp = wqkv + 4096 + (nb * 16 + c) * 64 + q * 8;
                bf16x8 w0 = *(const bf16x8*)(wp);
                bf16x8 w1 = *(const bf16x8*)(wp + 32);
                f32x4 a2 = (f32x4){0.f, 0.f, 0.f, 0.f};
                a2 = MFMA_B16(xa[g][0], w0, a2);
                a2 = MFMA_B16(xa[g][1], w1, a2);
                unsigned u01 = pack2(a2[0], a2[1]);
                unsigned u23 = pack2(a2[2], a2[3]);
                const int d = nb * 16 + c;
                const int kr = 4 * q;
                kw[(kr + 0) * 64 + (d ^ mk0)] = (unsigned short)u01;
                kw[(kr + 1) * 64 + (d ^ mk1)] = (unsigned short)(u01 >> 16);
                kw[(kr + 2) * 64 + (d ^ mk2)] = (unsigned short)u23;
                kw[(kr + 3) * 64 + (d ^ mk3)] = (unsigned short)(u23 >> 16);
            }
            en[g] = (f32x4){0.f, 0.f, 0.f, 0.f};
            const unsigned short* qrow = out2s + (size_t)(2 * c + e) * 1024
                                               + (gc0 + 2 * p + g) * 64;
            #pragma unroll
            for (int kc2 = 0; kc2 < 2; ++kc2) {
                const int L = kc2 * 32 + q * 8;
                bf16x8 ka = *(const bf16x8*)(kw + c * 64 + (L ^ mkw));
                bf16x8 qb = *(const bf16x8*)(qrow + (L ^ mqe));
                en[g] = MFMA_B16(ka, qb, en[g]);
            }
        }
        // lane(q,c): en[g][r] = energy[i=c][j=4q+r]

        // ---- softmax (both groups) ----
        unsigned pa0[2], pa1[2];
        #pragma unroll
        for (int g = 0; g < 2; ++g) {
            float mx = fmaxf(fmaxf(en[g][0], en[g][1]), fmaxf(en[g][2], en[g][3]));
            mx = fmaxf(mx, __shfl_xor(mx, 16));
            mx = fmaxf(mx, __shfl_xor(mx, 32));
            float p0 = exp2f((en[g][0] - mx) * SCL);
            float p1 = exp2f((en[g][1] - mx) * SCL);
            float p2 = exp2f((en[g][2] - mx) * SCL);
            float p3 = exp2f((en[g][3] - mx) * SCL);
            float s = p0 + p1 + p2 + p3;
            s += __shfl_xor(s, 16);
            s += __shfl_xor(s, 32);
            float rinv = 1.0f / s;
            pa0[g] = pack2(p0 * rinv, p1 * rinv);   // j = 4q+0,1
            pa1[g] = pack2(p2 * rinv, p3 * rinv);   // j = 4q+2,3
        }

        // ---- PV (both groups); output overwrites the Q stripe ----
        const int sh0 = (32 * q + c) & 63;
        const int sh1 = (32 * q + 16 + c) & 63;
        const int sv0 = 32 * (q & 1) + c;
        const int sv1 = sv0 + 16;
        const bool hi = (q >= 2);                   // k >= 16 -> zero pad
        #pragma unroll
        for (int g = 0; g < 2; ++g) {
            int a0 = __shfl((int)pa0[g], sh0);
            int a1 = __shfl((int)pa1[g], sh0);
            int a2 = __shfl((int)pa0[g], sh1);
            int a3 = __shfl((int)pa1[g], sh1);
            uint4 A2u;
            A2u.x = hi ? 0u : (unsigned)a0;
            A2u.y = hi ? 0u : (unsigned)a1;
            A2u.z = hi ? 0u : (unsigned)a2;
            A2u.w = hi ? 0u : (unsigned)a3;
            bf16x8 A2 = __builtin_bit_cast(bf16x8, A2u);

            #pragma unroll
            for (int nb = 0; nb < 4; ++nb) {
                uint4 B2u;
                B2u.x = (unsigned)__shfl((int)pkV[g][nb].x, sv0);
                B2u.y = (unsigned)__shfl((int)pkV[g][nb].y, sv0);
                B2u.z = (unsigned)__shfl((int)pkV[g][nb].x, sv1);
                B2u.w = (unsigned)__shfl((int)pkV[g][nb].y, sv1);
                bf16x8 B2 = __builtin_bit_cast(bf16x8, B2u);
                f32x4 o = (f32x4){0.f, 0.f, 0.f, 0.f};
                o = MFMA_B16(A2, B2, o);
                unsigned u01 = pack2(o[0], o[1]);
                unsigned u23 = pack2(o[2], o[3]);
                const int d = nb * 16 + c;
                qs[g][(d ^ mS0)]            = (unsigned short)u01;
                qs[g][2048 + (d ^ mS1)]     = (unsigned short)(u01 >> 16);
                qs[g][4096 + (d ^ mS2)]     = (unsigned short)u23;
                qs[g][6144 + (d ^ mS3)]     = (unsigned short)(u23 >> 16);
            }
        }
    }

    __syncthreads();   // A-tile complete

    // ================= phase 2: GEMM  C[32][1024] = A @ Wo^T + bias =======
    // wave w: all 32 rows x cols [w*128, w*128+128). acc[2][8] = 64 VGPR.
    const unsigned short* gBw = wob + (size_t)(w * 8) * 512 + (size_t)l * 8;
    float bc[8];
    #pragma unroll
    for (int nb = 0; nb < 8; ++nb) bc[nb] = bias[w * 128 + nb * 16 + c];

    f32x4 acc[2][8];
    #pragma unroll
    for (int m = 0; m < 2; ++m)
        #pragma unroll
        for (int nb = 0; nb < 8; ++nb)
            acc[m][nb] = (f32x4){0.f, 0.f, 0.f, 0.f};

    const int ma0 = swz(c);                    // A-read masks (rows c, 16+c)
    const int ma1 = swz(16 + c);
    bf16x8 bE[8], bO[8], av[2];

    #pragma unroll
    for (int nb = 0; nb < 8; ++nb) bE[nb] = *(const bf16x8*)(gBw + nb * 512);   // kc=0

    #pragma unroll 1
    for (int tt = 0; tt < 16; ++tt) {
        const size_t kb = (size_t)tt * 65536;  // = (2tt) * 32768 shorts
        #pragma unroll
        for (int nb = 0; nb < 8; ++nb)          // prefetch odd kc = 2tt+1
            bO[nb] = *(const bf16x8*)(gBw + kb + 32768 + nb * 512);
        {
            const int L = (2 * tt) * 32 + q * 8;
            av[0] = *(const bf16x8*)(out2s + (size_t)(c) * 1024 + (L ^ ma0));
            av[1] = *(const bf16x8*)(out2s + (size_t)(16 + c) * 1024 + (L ^ ma1));
            #pragma unroll
            for (int m = 0; m < 2; ++m)
                #pragma unroll
                for (int nb = 0; nb < 8; ++nb)
                    acc[m][nb] = MFMA_B16(av[m], bE[nb], acc[m][nb]);
        }
        if (tt < 15) {
            #pragma unroll
            for (int nb = 0; nb < 8; ++nb)      // prefetch even kc = 2tt+2
                bE[nb] = *(const bf16x8*)(gBw + kb + 65536 + nb * 512);
        }
        {
            const int L = (2 * tt + 1) * 32 + q * 8;
            av[0] = *(const bf16x8*)(out2s + (size_t)(c) * 1024 + (L ^ ma0));
            av[1] = *(const bf16x8*)(out2s + (size_t)(16 + c) * 1024 + (L ^ ma1));
            #pragma unroll
            for (int m = 0; m < 2; ++m)
                #pragma unroll
                for (int nb = 0; nb < 8; ++nb)
                    acc[m][nb] = MFMA_B16(av[m], bO[nb], acc[m][nb]);
        }
    }

    // ---- epilogue: bias + fp32 store. Local row lr = m*16 + q*4 + r ->
    //      global row rg = batch*512 + 2*h16 + (lr&1) + 32*(lr>>1).
    #pragma unroll
    for (int m = 0; m < 2; ++m) {
        #pragma unroll
        for (int r = 0; r < 4; ++r) {
            const int lr = m * 16 + q * 4 + r;
            const int rg = batch * 512 + 2 * h16 + (lr & 1) + 32 * (lr >> 1);
            float* cp2 = C + (size_t)rg * 1024 + w * 128 + c;
            #pragma unroll
            for (int nb = 0; nb < 8; ++nb)
                cp2[nb * 16] = acc[m][nb][r] + bc[nb];
        }
    }
}

// ---------------------------------------------------------------------------
extern "C" void kernel_launch(void* const* d_in, const int* in_sizes, int n_in,
                              void* d_out, int out_size, void* d_ws, size_t ws_size,
                              hipStream_t stream) {
    const float* x  = (const float*)d_in[0];
    const float* wq = (const float*)d_in[1];
    const float* wk = (const float*)d_in[2];
    const float* wv = (const float*)d_in[3];
    const float* wo = (const float*)d_in[4];
    const float* bo = (const float*)d_in[5];
    float* out = (float*)d_out;

    unsigned short* wob   = (unsigned short*)d_ws;           // 1024*1024 bf16 packed (2 MB)
    unsigned short* wqkvb = wob + (size_t)EMB * EMB;         // 3*4096 bf16 (24 KB)

    static int s_once = []() {
        hipFuncSetAttribute((const void*)k_mega,
                            hipFuncAttributeMaxDynamicSharedMemorySize, 81920);
        return 0;
    }();
    (void)s_once;

    k_cvt <<<524, 256, 0, stream>>>(wo, wq, wk, wv, wob, wqkvb);
    k_mega<<<512, 512, 81920, stream>>>(x, wqkvb, wob, bo, out);
}

// Round 14
// 152.608 us; speedup vs baseline: 1.3610x; 1.1478x over previous
//
#include <hip/hip_runtime.h>
#include <hip/hip_bf16.h>
#include <stdint.h>

// Problem constants
#define TOKS   262144      // B*S = 32*8192
#define NGRP   16384       // B*G = 32*512
#define EMB    1024
#define HD     64

using bf16x8 = __attribute__((ext_vector_type(8))) short;   // 8 bf16 (4 VGPRs) MFMA operand
using f32x4  = __attribute__((ext_vector_type(4))) float;   // MFMA accumulator

__device__ __forceinline__ unsigned pack2(float a, float b) {
    union { __hip_bfloat162 h; unsigned u; } cvt;
    cvt.h = __float22bfloat162_rn(make_float2(a, b));   // RNE pk-convert
    return cvt.u;
}
__device__ __forceinline__ bf16x8 cvt8(float4 v0, float4 v1) {
    uint4 u;
    u.x = pack2(v0.x, v0.y);
    u.y = pack2(v0.z, v0.w);
    u.z = pack2(v1.x, v1.y);
    u.w = pack2(v1.z, v1.w);
    return __builtin_bit_cast(bf16x8, u);
}

// ---------------------------------------------------------------------------
// K0: pack Wo (fp32 [1024][1024]) into MFMA-fragment-linear bf16 (blocks 0..511):
//       packed[((kc*64 + nb)*64 + l)*8 + e] = bf16(Wo[nb*16 + (l&15)][kc*32 + (l>>4)*8 + e])
//     Wq|Wk|Wv (fp32 [64][64]) -> bf16 packed [3][4096] (blocks 512..523).
// ---------------------------------------------------------------------------
__global__ __launch_bounds__(256) void k_cvt(const float* __restrict__ wo,
                                             const float* __restrict__ wq,
                                             const float* __restrict__ wk,
                                             const float* __restrict__ wv,
                                             unsigned short* __restrict__ wob,
                                             unsigned short* __restrict__ wqkvb) {
    int bid = blockIdx.x;
    if (bid < 512) {
        int tid = bid * 256 + threadIdx.x;   // 0..131071, 8 elems each
        int kc  = tid >> 12;                 // k-chunk of 32, 0..31
        int nb  = (tid >> 6) & 63;           // n-block of 16
        int l   = tid & 63;                  // lane within fragment
        int n   = nb * 16 + (l & 15);
        int k   = kc * 32 + (l >> 4) * 8;
        const float* src = wo + (size_t)n * 1024 + k;
        float4 v0 = *(const float4*)(src);
        float4 v1 = *(const float4*)(src + 4);
        *(bf16x8*)(wob + (size_t)tid * 8) = cvt8(v0, v1);
    } else {
        int b = bid - 512;                  // 0..11
        int m = b >> 2;
        const float* src = (m == 0) ? wq : ((m == 1) ? wk : wv);
        int idx = ((b & 3) * 256 + threadIdx.x) * 4;
        float4 v = *(const float4*)(src + idx);
        uint2 p;
        p.x = pack2(v.x, v.y);
        p.y = pack2(v.z, v.w);
        *(uint2*)(wqkvb + m * 4096 + idx) = p;
    }
}

// ---------------------------------------------------------------------------
// K1 (MEGA): fully fused attention + output GEMM. Grid 256 blocks x 512 thr.
// REVERT to the round-6 configuration — best harness-verified (150.25us
// total, k_mega ~61us). Rounds 7-13 post-mortem: every attempt to overlap
// phase 1 (attention, additive-pipe-bound: VALU 13 + DS 12 + L2 6 + MFMA
// 4us) with phase 2 (GEMM, 17us MFMA + 15us L2 B-stream) was blocked by a
// measured constraint:
//   - in-wave pipelining (r8-r12): RA pins this kernel at 128 VGPR with
//     dynamic LDS (three mechanisms tried: launch_bounds(512,2)/(512,1),
//     amdgpu_waves_per_eu(1,2)) -> acc[4][8] spills, ~77MB scratch, 115us.
//   - half-block 2-blocks/CU (r13): 2x80KB did not co-schedule (occupancy
//     19.7 ~= 1-block baseline), B-stream doubled -> 85us.
//   - pair-interleave + better swizzle (r7): flat (conflicts 3.1M->1.8M,
//     60.5us ~= 61us).
// Block (batch = bid>>3, q8 = bid&7) owns 1024 contiguous tokens = 64
// groups, whose attention outputs form exactly 64 rows of out2, kept ONLY
// in LDS (128KB A-tile); then C[64][1024] = A @ Wo^T + bias directly.
// out2 never touches HBM. GEMM K-loop: no barriers, no staging; B = Wo
// register-streamed from the fragment-packed wob (L2-resident).
// LDS swizzle: physical_col = logical_col ^ ((row&7)<<3), write & read.
// ---------------------------------------------------------------------------
#define SCL 0.0450842200278f   /* log2(e)/32 */

#define MFMA_B16(A, B, Cc) __builtin_amdgcn_mfma_f32_16x16x32_bf16(A, B, Cc, 0, 0, 0)

__global__ __launch_bounds__(512, 2) void k_mega(const float* __restrict__ x,
                                                 const unsigned short* __restrict__ wqkv,
                                                 const unsigned short* __restrict__ wob,
                                                 const float* __restrict__ bias,
                                                 float* __restrict__ C) {
    extern __shared__ __align__(16) unsigned short lds[];
    unsigned short* out2s = lds;               // [64][1024] bf16 A-tile (128 KB)
    unsigned short* kscr  = lds + 65536;       // [8 waves][16][64] K-scratch (16 KB)

    const int t = threadIdx.x;
    const int w = t >> 6, l = t & 63;
    const int c = l & 15, q = l >> 4;
    const int bid   = blockIdx.x;
    const int batch = bid >> 3, q8 = bid & 7;
    unsigned short* kw = kscr + w * 1024;

    // ================= phase 1: attention (8 groups/wave, sequential) =====
    #pragma unroll 1
    for (int i = 0; i < 8; ++i) {
        const int gl   = w * 8 + i;            // local group 0..63
        const int gbq  = gl >> 4;              // local gb 0..3
        const int gcol = gl & 15;              // column stripe
        const size_t tok0 = (size_t)bid * 1024 + (size_t)gl * 16;

        // ---- x A-frags (fp32 -> bf16 in-register) ----
        bf16x8 xa[2];
        {
            const float* xp = x + (tok0 + c) * 64 + q * 8;
            #pragma unroll
            for (int kc = 0; kc < 2; ++kc) {
                float4 v0 = *(const float4*)(xp + kc * 32);
                float4 v1 = *(const float4*)(xp + kc * 32 + 4);
                xa[kc] = cvt8(v0, v1);
            }
        }

        // Q/O stripe base: rows 16q+gbq (+4,+8,+12), masks alternate even/odd token
        const int mQ0 = gbq << 3;              // (row&7)<<3 for tokens 4q+0, 4q+2
        const int mQ1 = 32 + (gbq << 3);       // for tokens 4q+1, 4q+3
        unsigned short* qslot = out2s + (size_t)(16 * q + gbq) * 1024 + gcol * 64;

        // ---- projections: Q -> A-tile stripe, K -> scratch, V -> regs ----
        uint2 pkV[4];
        #pragma unroll
        for (int m = 0; m < 3; ++m) {
            #pragma unroll
            for (int nb = 0; nb < 4; ++nb) {
                const unsigned short* wp = wqkv + m * 4096 + (nb * 16 + c) * 64 + q * 8;
                bf16x8 w0 = *(const bf16x8*)(wp);
                bf16x8 w1 = *(const bf16x8*)(wp + 32);
                f32x4 acc = (f32x4){0.f, 0.f, 0.f, 0.f};
                acc = MFMA_B16(xa[0], w0, acc);
                acc = MFMA_B16(xa[1], w1, acc);
                unsigned u01 = pack2(acc[0], acc[1]);
                unsigned u23 = pack2(acc[2], acc[3]);
                const int d = nb * 16 + c;
                if (m == 0) {
                    qslot[(d ^ mQ0)]              = (unsigned short)u01;
                    qslot[4 * 1024 + (d ^ mQ1)]   = (unsigned short)(u01 >> 16);
                    qslot[8 * 1024 + (d ^ mQ0)]   = (unsigned short)u23;
                    qslot[12 * 1024 + (d ^ mQ1)]  = (unsigned short)(u23 >> 16);
                } else if (m == 1) {
                    const int kr = 4 * q;
                    kw[(kr + 0) * 64 + (d ^ (((kr + 0) & 7) << 3))] = (unsigned short)u01;
                    kw[(kr + 1) * 64 + (d ^ (((kr + 1) & 7) << 3))] = (unsigned short)(u01 >> 16);
                    kw[(kr + 2) * 64 + (d ^ (((kr + 2) & 7) << 3))] = (unsigned short)u23;
                    kw[(kr + 3) * 64 + (d ^ (((kr + 3) & 7) << 3))] = (unsigned short)(u23 >> 16);
                } else {
                    pkV[nb].x = u01;    // tokens 4q+0,1
                    pkV[nb].y = u23;    // tokens 4q+2,3
                }
            }
        }

        // ---- energy^T[j][i]: A = K-frag (scratch), B = Q-frag (A-tile) ----
        f32x4 e = (f32x4){0.f, 0.f, 0.f, 0.f};
        {
            const int mq = ((c * 4 + gbq) & 7) << 3;
            const unsigned short* qrow = out2s + (size_t)(c * 4 + gbq) * 1024 + gcol * 64;
            #pragma unroll
            for (int kc = 0; kc < 2; ++kc) {
                const int L = kc * 32 + q * 8;
                bf16x8 ka = *(const bf16x8*)(kw + c * 64 + (L ^ ((c & 7) << 3)));
                bf16x8 qb = *(const bf16x8*)(qrow + (L ^ mq));
                e = MFMA_B16(ka, qb, e);
            }
        }
        // lane(q,c): e[r] = energy[i=c][j=4q+r]

        // ---- softmax over j ----
        unsigned pa0, pa1;
        {
            float mx = fmaxf(fmaxf(e[0], e[1]), fmaxf(e[2], e[3]));
            mx = fmaxf(mx, __shfl_xor(mx, 16));
            mx = fmaxf(mx, __shfl_xor(mx, 32));
            float p0 = exp2f((e[0] - mx) * SCL);
            float p1 = exp2f((e[1] - mx) * SCL);
            float p2 = exp2f((e[2] - mx) * SCL);
            float p3 = exp2f((e[3] - mx) * SCL);
            float s = p0 + p1 + p2 + p3;
            s += __shfl_xor(s, 16);
            s += __shfl_xor(s, 32);
            float rinv = 1.0f / s;
            pa0 = pack2(p0 * rinv, p1 * rinv);   // j = 4q+0,1
            pa1 = pack2(p2 * rinv, p3 * rinv);   // j = 4q+2,3
        }

        // ---- PV: output overwrites the Q stripe (Q dead after energy) ----
        {
            const int sh0 = (32 * q + c) & 63;
            const int sh1 = (32 * q + 16 + c) & 63;
            const int sv0 = 32 * (q & 1) + c;
            const int sv1 = sv0 + 16;
            const bool hi = (q >= 2);           // k >= 16 -> zero pad
            int a0 = __shfl((int)pa0, sh0);
            int a1 = __shfl((int)pa1, sh0);
            int a2 = __shfl((int)pa0, sh1);
            int a3 = __shfl((int)pa1, sh1);
            uint4 A2u;
            A2u.x = hi ? 0u : (unsigned)a0;
            A2u.y = hi ? 0u : (unsigned)a1;
            A2u.z = hi ? 0u : (unsigned)a2;
            A2u.w = hi ? 0u : (unsigned)a3;
            bf16x8 A2 = __builtin_bit_cast(bf16x8, A2u);

            #pragma unroll
            for (int nb = 0; nb < 4; ++nb) {
                uint4 B2u;
                B2u.x = (unsigned)__shfl((int)pkV[nb].x, sv0);
                B2u.y = (unsigned)__shfl((int)pkV[nb].y, sv0);
                B2u.z = (unsigned)__shfl((int)pkV[nb].x, sv1);
                B2u.w = (unsigned)__shfl((int)pkV[nb].y, sv1);
                bf16x8 B2 = __builtin_bit_cast(bf16x8, B2u);
                f32x4 o = (f32x4){0.f, 0.f, 0.f, 0.f};
                o = MFMA_B16(A2, B2, o);
                unsigned u01 = pack2(o[0], o[1]);
                unsigned u23 = pack2(o[2], o[3]);
                const int d = nb * 16 + c;
                qslot[(d ^ mQ0)]              = (unsigned short)u01;
                qslot[4 * 1024 + (d ^ mQ1)]   = (unsigned short)(u01 >> 16);
                qslot[8 * 1024 + (d ^ mQ0)]   = (unsigned short)u23;
                qslot[12 * 1024 + (d ^ mQ1)]  = (unsigned short)(u23 >> 16);
            }
        }
    }

    __syncthreads();   // A-tile complete

    // ================= phase 2: GEMM  C[64][1024] = A @ Wo^T + bias =======
    // wave w: all 64 rows x cols [w*128, w*128+128). No barriers, no staging.
    const unsigned short* gBw = wob + (size_t)(w * 8) * 512 + (size_t)l * 8;
    float bc[8];
    #pragma unroll
    for (int nb = 0; nb < 8; ++nb) bc[nb] = bias[w * 128 + nb * 16 + c];

    f32x4 acc[4][8];
    #pragma unroll
    for (int m = 0; m < 4; ++m)
        #pragma unroll
        for (int nb = 0; nb < 8; ++nb)
            acc[m][nb] = (f32x4){0.f, 0.f, 0.f, 0.f};

    const int axor = (c & 7) << 3;             // A-frag swizzle: rows m*16+c -> (row&7)=c&7
    bf16x8 bE[8], bO[8], a[4];

    #pragma unroll
    for (int nb = 0; nb < 8; ++nb) bE[nb] = *(const bf16x8*)(gBw + nb * 512);   // kc=0

    #pragma unroll 1
    for (int tt = 0; tt < 16; ++tt) {
        const size_t kb = (size_t)tt * 65536;
        #pragma unroll
        for (int nb = 0; nb < 8; ++nb)          // prefetch odd kc = 2tt+1
            bO[nb] = *(const bf16x8*)(gBw + kb + 32768 + nb * 512);
        {
            const int L = (2 * tt) * 32 + q * 8;
            #pragma unroll
            for (int m = 0; m < 4; ++m)
                a[m] = *(const bf16x8*)(out2s + (size_t)(m * 16 + c) * 1024 + (L ^ axor));
            #pragma unroll
            for (int m = 0; m < 4; ++m)
                #pragma unroll
                for (int nb = 0; nb < 8; ++nb)
                    acc[m][nb] = MFMA_B16(a[m], bE[nb], acc[m][nb]);
        }
        if (tt < 15) {
            #pragma unroll
            for (int nb = 0; nb < 8; ++nb)      // prefetch even kc = 2tt+2
                bE[nb] = *(const bf16x8*)(gBw + kb + 65536 + nb * 512);
        }
        {
            const int L = (2 * tt + 1) * 32 + q * 8;
            #pragma unroll
            for (int m = 0; m < 4; ++m)
                a[m] = *(const bf16x8*)(out2s + (size_t)(m * 16 + c) * 1024 + (L ^ axor));
            #pragma unroll
            for (int m = 0; m < 4; ++m)
                #pragma unroll
                for (int nb = 0; nb < 8; ++nb)
                    acc[m][nb] = MFMA_B16(a[m], bO[nb], acc[m][nb]);
        }
    }

    // ---- epilogue: bias + fp32 store. Global C row for local row lr =
    // m*16 + q*4 + r:  rg = batch*512 + (lr>>2)*32 + q8*4 + (lr&3).
    #pragma unroll
    for (int m = 0; m < 4; ++m) {
        #pragma unroll
        for (int r = 0; r < 4; ++r) {
            const int rg = batch * 512 + (m * 4 + q) * 32 + q8 * 4 + r;
            float* cp = C + (size_t)rg * 1024 + w * 128 + c;
            #pragma unroll
            for (int nb = 0; nb < 8; ++nb)
                cp[nb * 16] = acc[m][nb][r] + bc[nb];
        }
    }
}

// ---------------------------------------------------------------------------
extern "C" void kernel_launch(void* const* d_in, const int* in_sizes, int n_in,
                              void* d_out, int out_size, void* d_ws, size_t ws_size,
                              hipStream_t stream) {
    const float* x  = (const float*)d_in[0];
    const float* wq = (const float*)d_in[1];
    const float* wk = (const float*)d_in[2];
    const float* wv = (const float*)d_in[3];
    const float* wo = (const float*)d_in[4];
    const float* bo = (const float*)d_in[5];
    float* out = (float*)d_out;

    unsigned short* wob   = (unsigned short*)d_ws;           // 1024*1024 bf16 packed (2 MB)
    unsigned short* wqkvb = wob + (size_t)EMB * EMB;         // 3*4096 bf16 (24 KB)

    static int s_once = []() {
        hipFuncSetAttribute((const void*)k_mega,
                            hipFuncAttributeMaxDynamicSharedMemorySize, 147456);
        return 0;
    }();
    (void)s_once;

    k_cvt <<<524, 256, 0, stream>>>(wo, wq, wk, wv, wob, wqkvb);
    k_mega<<<256, 512, 147456, stream>>>(x, wqkvb, wob, bo, out);
}